// Round 4
// baseline (110.593 us; speedup 1.0000x reference)
//
#include <hip/hip_runtime.h>

// Problem constants
#define N_PIX 4096   // 64*64 pixels
#define N_D   256    // feature dims
#define N_C   19     // classes
#define N_B   51     // bins
#define CACHE 6      // register-cached pixel chunks (covers m <= 384; data has ~215)
#define N_BLOCKS_MAIN (18 * 64)

// ws layout (bytes)
#define OFF_LIST   0                      // int  [19][4096]
#define OFF_COUNTS 311296                 // int  [19]
#define OFF_ACC    311424                 // float[1]
#define OFF_TICKET 311428                 // int[1]

// --- K1: bucket pixel indices by class (blocks 0..18) + feature copy (19..255)
__global__ __launch_bounds__(256) void k_pre(const float* __restrict__ feature,
                                             const int* __restrict__ label,
                                             float* __restrict__ out,
                                             int* __restrict__ list,
                                             int* __restrict__ counts,
                                             float* __restrict__ acc,
                                             int* __restrict__ ticket) {
    const int b = blockIdx.x;
    if (b < N_C) {
        // ---- bucket class b: deterministic 4-wave compaction ----
        const int c = b;
        const int w = threadIdx.x >> 6;
        const int lane = threadIdx.x & 63;
        __shared__ int wcnt[4];
        if (c == 0 && threadIdx.x == 0) { *acc = 0.f; *ticket = 0; }  // ws poisoned

        const int q0 = w * 1024;   // phase 1: count matches in my quarter
        int cnt = 0;
        for (int base = 0; base < 1024; base += 64) {
            cnt += (int)__popcll(__ballot(label[q0 + base + lane] == c));
        }
        if (lane == 0) wcnt[w] = cnt;
        __syncthreads();
        int m = 0;
#pragma unroll
        for (int i = 0; i < 4; ++i) m += (i < w) ? wcnt[i] : 0;

        for (int base = 0; base < 1024; base += 64) {  // phase 2: scatter
            const int n = q0 + base + lane;
            const bool match = (label[n] == c);
            const unsigned long long mask = __ballot(match);
            if (match) list[c * N_PIX + m + __popcll(mask & ((1ull << lane) - 1ull))] = n;
            m += (int)__popcll(mask);
        }
        if (w == 3 && lane == 0) counts[c] = m;
    } else {
        // ---- feature pass-through: out[1..] = feature[0..] ----
        // out+1 is 4B-misaligned for float4 -> float4 loads, scalar stores.
        const int tid = (b - N_C) * 256 + threadIdx.x;
        const int nth = (256 - N_C) * 256;
        const float4* __restrict__ src = (const float4*)feature;
        float* __restrict__ dst = out + 1;
        for (int i = tid; i < N_PIX * N_D / 4; i += nth) {
            const float4 v = src[i];
            dst[4 * i + 0] = v.x;
            dst[4 * i + 1] = v.y;
            dst[4 * i + 2] = v.z;
            dst[4 * i + 3] = v.w;
        }
    }
}

// --- K2 (fused stats + KDE + normalize + smooth-L1 + finalize) ---
// grid = (18, 64), block 256 = 4 waves; wave = one (c,d) row.
// LANE-OWNS-PIXEL: each lane accumulates all 51 bins for its own pixels in
// registers (no cross-lane traffic in the hot loop); one butterfly reduce per
// wave at the end. Norm factors 1/sqrt(2*pi*v) cancel after row norm -> dropped.
__global__ __launch_bounds__(256) void k_main(const float* __restrict__ feature,
                                              const int* __restrict__ list,
                                              const int* __restrict__ counts,
                                              float* __restrict__ acc,
                                              int* __restrict__ ticket,
                                              float* __restrict__ out) {
    const int c = blockIdx.x + 1;                 // class 0 never reaches the loss
    const int w = threadIdx.x >> 6;
    const int d = blockIdx.y * 4 + w;
    const int lane = threadIdx.x & 63;
    const int m = counts[c];
    __shared__ float blk[4];
    float part = 0.f;
    if (m > 0) {                                  // block-uniform branch
        const float* __restrict__ row = feature + d * N_PIX;  // F[:,d] contiguous
        const int* __restrict__ lst = list + c * N_PIX;
        const int nch = (m + 63) >> 6;

        // -- gather own pixels (register cache) + stats in one pass --
        // tail pad f=-1e18: exp2(as*t*t) -> exp2(-inf) -> 0 in the KDE loop
        float fc[CACHE];
        float s1 = 0.f, s2 = 0.f;
        for (int ch = 0; ch < nch; ++ch) {
            const int j = (ch << 6) + lane;
            const bool valid = (j < m);
            const float f = valid ? row[lst[j]] : -1e18f;
            if (ch < CACHE) fc[ch] = f;
            s1 += valid ? f : 0.f;
            s2 += valid ? f * f : 0.f;
        }
#pragma unroll
        for (int off = 32; off; off >>= 1) {
            s1 += __shfl_xor(s1, off);
            s2 += __shfl_xor(s2, off);
        }
        const float cnt = (float)m;
        const float mu = s1 / cnt;
        const float v = fmaxf(s2 / cnt - mu * mu, 1e-12f);

        const float LOG2E = 1.44269504088896340736f;
        const float as = -12.5f * LOG2E / v;   // sample kernel: var/25 -> -0.5*25/v
        const float at = -0.5f * LOG2E / v;    // target

        // -- KDE: per-lane 51-bin register accumulators, zero cross-lane ops --
        float a[N_B];
#pragma unroll
        for (int b = 0; b < N_B; ++b) a[b] = 0.f;
        for (int ch = 0; ch < nch; ++ch) {
            float f;
            if (ch < CACHE) f = fc[ch];
            else {  // overflow path (not hit for this data; correctness guard)
                const int j = (ch << 6) + lane;
                f = (j < m) ? row[lst[j]] : -1e18f;
            }
#pragma unroll
            for (int b = 0; b < N_B; ++b) {
                const float bin = -5.0f + 0.2f * (float)b;  // compile-time const
                const float t = f - bin;
                a[b] += __builtin_amdgcn_exp2f(as * t * t);
            }
        }

        // -- once-per-wave cross-lane reduction of the 51 bins --
#pragma unroll
        for (int b = 0; b < N_B; ++b) {
#pragma unroll
            for (int off = 32; off; off >>= 1) a[b] += __shfl_xor(a[b], off);
        }

        // -- normalize + smooth-L1 (wave-uniform; computed redundantly/lane) --
        float ss = 0.f, st = 0.f;
#pragma unroll
        for (int b = 0; b < N_B; ++b) {
            ss += a[b];
            const float tt = (-5.0f + 0.2f * (float)b) - mu;
            st += __builtin_amdgcn_exp2f(at * tt * tt);
        }
        const float is = 1.f / fmaxf(ss, 1e-30f);
        const float it = 1.f / fmaxf(st, 1e-30f);
        float sl1 = 0.f;
#pragma unroll
        for (int b = 0; b < N_B; ++b) {
            const float tt = (-5.0f + 0.2f * (float)b) - mu;
            const float tg = __builtin_amdgcn_exp2f(at * tt * tt) * it;
            const float diff = a[b] * is - tg;
            const float ad = fabsf(diff);
            sl1 += (ad < 1.f) ? 0.5f * diff * diff : ad - 0.5f;
        }
        part = sl1;   // identical on every lane
    }
    if (lane == 0) blk[w] = part;
    __syncthreads();  // m is block-uniform -> no divergent barrier
    if (threadIdx.x == 0) {
        atomicAdd(acc, blk[0] + blk[1] + blk[2] + blk[3]);
        __threadfence();                       // order acc-add before ticket-add
        const int t = atomicAdd(ticket, 1);    // device-scope
        if (t == N_BLOCKS_MAIN - 1) {          // I'm last: finalize
            int active = 0;
            for (int cc = 1; cc < N_C; ++cc) active += (counts[cc] > 0) ? 1 : 0;
            const float total = atomicAdd(acc, 0.0f);  // coherent read
            out[0] = total / (float)(N_D * N_B) / ((float)active + 1e-12f);
        }
    }
}

extern "C" void kernel_launch(void* const* d_in, const int* in_sizes, int n_in,
                              void* d_out, int out_size, void* d_ws, size_t ws_size,
                              hipStream_t stream) {
    const float* feature = (const float*)d_in[0];   // [1,256,64,64] fp32
    const int* label = (const int*)d_in[1];         // [1,1,64,64] int32
    float* out = (float*)d_out;                     // [0]=loss, [1..]=feature passthrough
    char* ws = (char*)d_ws;
    int* list = (int*)(ws + OFF_LIST);
    int* counts = (int*)(ws + OFF_COUNTS);
    float* acc = (float*)(ws + OFF_ACC);
    int* ticket = (int*)(ws + OFF_TICKET);

    k_pre<<<256, 256, 0, stream>>>(feature, label, out, list, counts, acc, ticket);
    dim3 grid(N_C - 1, N_D / 4);
    k_main<<<grid, 256, 0, stream>>>(feature, list, counts, acc, ticket, out);
}